// Round 3
// baseline (389.740 us; speedup 1.0000x reference)
//
#include <hip/hip_runtime.h>
#include <math.h>

#define N_NODES 50000
#define N_EDGES 800000
#define DIN 256
#define DHID 128
#define DOUT 64
// Padded CSR row stride. In-degree is Binomial(800000, 1/50000) ~ Poisson(16);
// P(deg > 64) ~ 1e-19 per node -> stride 64 is safe.
#define CSTRIDE 64
#define HBLOCKS 256
#define HCHUNK (N_EDGES / HBLOCKS)     // 3125 exactly
#define HWORDS (N_NODES / 4)           // 12500 packed byte-counters per block

// ---------------- setup kernels ----------------

__global__ void k_init(int* deg_in, int n) {
    int i = blockIdx.x * 256 + threadIdx.x;
    if (i < n) deg_in[i] = 0;
}

// out-degree histogram, LDS-privatized, byte-packed (4 bins per u32).
// Per-block per-node counts are <= max total degree (~45) << 255, so no byte carry.
__global__ void k_hist(const int* __restrict__ src, unsigned int* __restrict__ partials) {
    __shared__ unsigned int h[HWORDS];
    int t = threadIdx.x;
    for (int w = t; w < HWORDS; w += 256) h[w] = 0u;
    __syncthreads();
    int base = blockIdx.x * HCHUNK;
    for (int idx = t; idx < HCHUNK; idx += 256) {
        int s = src[base + idx];
        atomicAdd(&h[s >> 2], 1u << ((s & 3) << 3));
    }
    __syncthreads();
    unsigned int* outp = partials + (size_t)blockIdx.x * HWORDS;
    for (int w = t; w < HWORDS; w += 256) outp[w] = h[w];
}

// sum the 256 partial histograms -> deg_out (4 nodes per thread, coalesced)
__global__ void k_hreduce(const unsigned int* __restrict__ partials, int* __restrict__ deg_out) {
    int wid = blockIdx.x * 256 + threadIdx.x;
    if (wid >= HWORDS) return;
    unsigned int s0 = 0, s1 = 0, s2 = 0, s3 = 0;
#pragma unroll 4
    for (int b = 0; b < HBLOCKS; ++b) {
        unsigned int w = partials[(size_t)b * HWORDS + wid];
        s0 += w & 0xffu; s1 += (w >> 8) & 0xffu;
        s2 += (w >> 16) & 0xffu; s3 += w >> 24;
    }
    int4 o; o.x = (int)s0; o.y = (int)s1; o.z = (int)s2; o.w = (int)s3;
    *(int4*)(deg_out + (wid << 2)) = o;
}

// One pass over edges: claim a slot in dst's padded bucket (the only global atomic),
// write the source index (ushort: N=50000 < 65536).
__global__ void k_count_fill(const int* __restrict__ src, const int* __restrict__ dst,
                             int* deg_in, unsigned short* __restrict__ csr, int e) {
    int i = blockIdx.x * 256 + threadIdx.x;
    if (i < e) {
        int s = src[i], d = dst[i];
        int p = atomicAdd(&deg_in[d], 1);
        csr[(d << 6) + p] = (unsigned short)s;
    }
}

__global__ void k_norms(const int* __restrict__ deg_out, const int* __restrict__ deg_in,
                        float* ns, float* nd, float* c, int n) {
    int i = blockIdx.x * 256 + threadIdx.x;
    if (i < n) {
        int dov = deg_out[i]; if (dov < 1) dov = 1;
        int div_ = deg_in[i]; if (div_ < 1) div_ = 1;
        float a = 1.0f / sqrtf((float)dov);
        float b = 1.0f / sqrtf((float)div_);
        ns[i] = a; nd[i] = b; c[i] = a * b;
    }
}

// ---------------- weight folding: W13 = W1@W3 (blocks 0..63), bb = b1@W3 (block 64) ----

__global__ void k_weights(const float* __restrict__ W1, const float* __restrict__ b1,
                          const float* __restrict__ W3,
                          float* __restrict__ W13, float* __restrict__ bb) {
    if (blockIdx.x == 64) {
        int j = threadIdx.x;
        if (j < DOUT) {
            float s = 0.f;
            for (int k = 0; k < DHID; ++k) s += b1[k] * W3[k * DOUT + j];
            bb[j] = s;
        }
        return;
    }
    int idx = blockIdx.x * 256 + threadIdx.x;  // 16384 outputs
    int i = idx >> 6, j = idx & 63;
    float s = 0.f;
    for (int k = 0; k < DHID; ++k) s += W1[i * DHID + k] * W3[k * DOUT + j];
    W13[idx] = s;
}

// ---------------- dense GEMM: Y[50000,64] = ns ∘ (X[50000,256] @ W13[256,64]) ----------------

__global__ void k_gemm(const float* __restrict__ X, const float* __restrict__ W13,
                       const float* __restrict__ ns, float* __restrict__ Y) {
    __shared__ float As[16][68];   // [k][row], padded
    __shared__ float Bs[16][64];   // [k][col]
    int tid = threadIdx.x;
    int tx = tid & 15, ty = tid >> 4;
    int row0 = blockIdx.x * 64;
    float acc[4][4];
#pragma unroll
    for (int i = 0; i < 4; ++i)
#pragma unroll
        for (int j = 0; j < 4; ++j) acc[i][j] = 0.f;

    int lr = tid >> 2;            // 0..63 row within tile
    int lk = (tid & 3) << 2;      // 0,4,8,12
    int arow = row0 + lr;
    if (arow > N_NODES - 1) arow = N_NODES - 1;   // clamp: garbage rows never stored

    for (int k0 = 0; k0 < DIN; k0 += 16) {
        float4 a = *(const float4*)(X + (size_t)arow * DIN + k0 + lk);
        As[lk + 0][lr] = a.x; As[lk + 1][lr] = a.y;
        As[lk + 2][lr] = a.z; As[lk + 3][lr] = a.w;
        float4 b = *(const float4*)(W13 + (size_t)(k0 + (tid >> 4)) * DOUT + ((tid & 15) << 2));
        *(float4*)&Bs[tid >> 4][(tid & 15) << 2] = b;
        __syncthreads();
#pragma unroll
        for (int k = 0; k < 16; ++k) {
            float4 av = *(const float4*)&As[k][ty << 2];
            float4 bv = *(const float4*)&Bs[k][tx << 2];
            float ar[4] = {av.x, av.y, av.z, av.w};
            float br[4] = {bv.x, bv.y, bv.z, bv.w};
#pragma unroll
            for (int i = 0; i < 4; ++i)
#pragma unroll
                for (int j = 0; j < 4; ++j) acc[i][j] += ar[i] * br[j];
        }
        __syncthreads();
    }
#pragma unroll
    for (int i = 0; i < 4; ++i) {
        int row = row0 + (ty << 2) + i;
        if (row < N_NODES) {
            float nsr = ns[row];
            float4 o;
            o.x = acc[i][0] * nsr; o.y = acc[i][1] * nsr;
            o.z = acc[i][2] * nsr; o.w = acc[i][3] * nsr;
            *(float4*)(Y + (size_t)row * DOUT + (tx << 2)) = o;
        }
    }
}

// ---------------- pull-mode SpMM, D=64: TWO nodes per wave, lane = column ----------------
// Edge lists come in as one coalesced 128B ushort load per node; per-edge source
// indices are broadcast with v_readlane (wave-uniform j) -> scalar base + lane offset
// saddr loads, 8 gathers in flight.
// MODE 0: first pass  y = c*acc + ns*bb[lane]
// MODE 1: middle pass y = c*acc
// MODE 2: final pass  y = nd*acc + b3[lane]

template <int MODE>
__global__ void k_spmm(const float* __restrict__ x, float* __restrict__ y,
                       const unsigned short* __restrict__ csr,
                       const int* __restrict__ cnt,
                       const float* __restrict__ c, const float* __restrict__ ns,
                       const float* __restrict__ nd,
                       const float* __restrict__ bb, const float* __restrict__ b3) {
    int wave = threadIdx.x >> 6;
    int lane = threadIdx.x & 63;
    int node0 = (blockIdx.x * 4 + wave) * 2;   // grid = N/8 exactly
    int node1 = node0 + 1;
    int n0 = cnt[node0], n1 = cnt[node1];
    int s0v = csr[(node0 << 6) + lane];
    int s1v = csr[(node1 << 6) + lane];
    const float* xl = x + lane;
    float acc0 = 0.f, acc1 = 0.f;
    int m = (n0 < n1) ? n0 : n1;
    int j = 0;
    for (; j + 4 <= m; j += 4) {
        int a0 = __builtin_amdgcn_readlane(s0v, j);
        int a1 = __builtin_amdgcn_readlane(s0v, j + 1);
        int a2 = __builtin_amdgcn_readlane(s0v, j + 2);
        int a3 = __builtin_amdgcn_readlane(s0v, j + 3);
        int b0 = __builtin_amdgcn_readlane(s1v, j);
        int b1 = __builtin_amdgcn_readlane(s1v, j + 1);
        int b2 = __builtin_amdgcn_readlane(s1v, j + 2);
        int b3v = __builtin_amdgcn_readlane(s1v, j + 3);
        float t0 = xl[a0 << 6];
        float t1 = xl[a1 << 6];
        float t2 = xl[a2 << 6];
        float t3 = xl[a3 << 6];
        float u0 = xl[b0 << 6];
        float u1 = xl[b1 << 6];
        float u2 = xl[b2 << 6];
        float u3 = xl[b3v << 6];
        acc0 += t0; acc0 += t1; acc0 += t2; acc0 += t3;
        acc1 += u0; acc1 += u1; acc1 += u2; acc1 += u3;
    }
    for (int ja = j; ja < n0; ++ja) acc0 += xl[__builtin_amdgcn_readlane(s0v, ja) << 6];
    for (int jb = j; jb < n1; ++jb) acc1 += xl[__builtin_amdgcn_readlane(s1v, jb) << 6];

    float r0, r1;
    if (MODE == 0)      { float bl = bb[lane]; r0 = c[node0] * acc0 + ns[node0] * bl;
                                               r1 = c[node1] * acc1 + ns[node1] * bl; }
    else if (MODE == 1) { r0 = c[node0] * acc0; r1 = c[node1] * acc1; }
    else                { float bl = b3[lane]; r0 = nd[node0] * acc0 + bl;
                                               r1 = nd[node1] * acc1 + bl; }
    y[(node0 << 6) + lane] = r0;
    y[(node1 << 6) + lane] = r1;
}

// ---------------- launcher ----------------

extern "C" void kernel_launch(void* const* d_in, const int* in_sizes, int n_in,
                              void* d_out, int out_size, void* d_ws, size_t ws_size,
                              hipStream_t stream) {
    const float* X   = (const float*)d_in[0];
    const int*   src = (const int*)d_in[1];
    const int*   dst = (const int*)d_in[2];
    const float* W1  = (const float*)d_in[3];
    const float* b1  = (const float*)d_in[4];
    const float* W3  = (const float*)d_in[5];
    const float* b3  = (const float*)d_in[6];
    float* out = (float*)d_out;

    char* ws = (char*)d_ws;
    size_t off = 0;
    auto alloc = [&](size_t bytes) -> void* {
        void* p = ws + off;
        off = (off + bytes + 255) & ~(size_t)255;
        return p;
    };
    int*            deg_out  = (int*)alloc((size_t)N_NODES * 4);
    int*            deg_in   = (int*)alloc((size_t)N_NODES * 4);  // slot counter == in-degree
    unsigned short* csr      = (unsigned short*)alloc((size_t)N_NODES * CSTRIDE * 2);
    unsigned int*   partials = (unsigned int*)alloc((size_t)HBLOCKS * HWORDS * 4);  // 12.8 MB
    float*          ns       = (float*)alloc((size_t)N_NODES * 4);
    float*          nd       = (float*)alloc((size_t)N_NODES * 4);
    float*          cc       = (float*)alloc((size_t)N_NODES * 4);
    float*          W13      = (float*)alloc((size_t)DIN * DOUT * 4);
    float*          bb       = (float*)alloc(DOUT * 4);
    float*          Y0       = (float*)alloc((size_t)N_NODES * DOUT * 4);
    float*          Y1       = (float*)alloc((size_t)N_NODES * DOUT * 4);

    const int nblk = (N_NODES + 255) / 256;   // 196
    const int eblk = (N_EDGES + 255) / 256;   // 3125

    k_init<<<nblk, 256, 0, stream>>>(deg_in, N_NODES);
    k_hist<<<HBLOCKS, 256, 0, stream>>>(src, partials);
    k_hreduce<<<(HWORDS + 255) / 256, 256, 0, stream>>>(partials, deg_out);
    k_count_fill<<<eblk, 256, 0, stream>>>(src, dst, deg_in, csr, N_EDGES);
    k_norms<<<nblk, 256, 0, stream>>>(deg_out, deg_in, ns, nd, cc, N_NODES);

    k_weights<<<65, 256, 0, stream>>>(W1, b1, W3, W13, bb);

    // Y0 = ns ∘ (X @ (W1@W3))
    k_gemm<<<(N_NODES + 63) / 64, 256, 0, stream>>>(X, W13, ns, Y0);

    // 6 propagation passes; bias bb injected in pass 1, b3 in pass 6
    k_spmm<0><<<N_NODES / 8, 256, 0, stream>>>(Y0, Y1, csr, deg_in, cc, ns, nd, bb, b3);
    k_spmm<1><<<N_NODES / 8, 256, 0, stream>>>(Y1, Y0, csr, deg_in, cc, ns, nd, bb, b3);
    k_spmm<1><<<N_NODES / 8, 256, 0, stream>>>(Y0, Y1, csr, deg_in, cc, ns, nd, bb, b3);
    k_spmm<1><<<N_NODES / 8, 256, 0, stream>>>(Y1, Y0, csr, deg_in, cc, ns, nd, bb, b3);
    k_spmm<1><<<N_NODES / 8, 256, 0, stream>>>(Y0, Y1, csr, deg_in, cc, ns, nd, bb, b3);
    k_spmm<2><<<N_NODES / 8, 256, 0, stream>>>(Y1, out, csr, deg_in, cc, ns, nd, bb, b3);
}

// Round 4
// 350.391 us; speedup vs baseline: 1.1123x; 1.1123x over previous
//
#include <hip/hip_runtime.h>
#include <math.h>

#define N_NODES 50000
#define N_EDGES 800000
#define DIN 256
#define DHID 128
#define DOUT 64
// Padded CSR row stride. In-degree is Binomial(800000, 1/50000) ~ Poisson(16);
// P(deg > 64) ~ 1e-19 per node -> stride 64 is safe.
#define CSTRIDE 64
#define ZROW N_NODES            // sentinel row (kept zero) for padding to unroll multiple
#define HBLOCKS 256
#define HCHUNK (N_EDGES / HBLOCKS)     // 3125 exactly
#define HWORDS (N_NODES / 4)           // 12500 packed byte-counters per block

// ---------------- CSR build: histogram / prefix / LDS-atomic fill ----------------

// byte-packed LDS-privatized histogram (4 bins per u32). Per-block per-node
// counts <= total degree (~45-64) << 255 -> no byte carry.
__global__ void k_hist(const int* __restrict__ idx, unsigned int* __restrict__ partials) {
    __shared__ unsigned int h[HWORDS];
    int t = threadIdx.x;
    for (int w = t; w < HWORDS; w += 256) h[w] = 0u;
    __syncthreads();
    int base = blockIdx.x * HCHUNK;
    for (int i = t; i < HCHUNK; i += 256) {
        int s = idx[base + i];
        atomicAdd(&h[s >> 2], 1u << ((s & 3) << 3));
    }
    __syncthreads();
    unsigned int* outp = partials + (size_t)blockIdx.x * HWORDS;
    for (int w = t; w < HWORDS; w += 256) outp[w] = h[w];
}

// sum the 256 partial histograms -> deg (4 nodes per thread, coalesced)
__global__ void k_hreduce(const unsigned int* __restrict__ partials, int* __restrict__ deg) {
    int wid = blockIdx.x * 256 + threadIdx.x;
    if (wid >= HWORDS) return;
    unsigned int s0 = 0, s1 = 0, s2 = 0, s3 = 0;
#pragma unroll 4
    for (int b = 0; b < HBLOCKS; ++b) {
        unsigned int w = partials[(size_t)b * HWORDS + wid];
        s0 += w & 0xffu; s1 += (w >> 8) & 0xffu;
        s2 += (w >> 16) & 0xffu; s3 += w >> 24;
    }
    int4 o; o.x = (int)s0; o.y = (int)s1; o.z = (int)s2; o.w = (int)s3;
    *(int4*)(deg + (wid << 2)) = o;
}

// exclusive prefix along the block axis (packed bytes; totals <= 64 so packed
// adds never carry). Also emits the final in-degree.
__global__ void k_hprefix(const unsigned int* __restrict__ partials,
                          unsigned int* __restrict__ prefix, int* __restrict__ deg) {
    int wid = blockIdx.x * 256 + threadIdx.x;
    if (wid >= HWORDS) return;
    unsigned int run = 0;
    for (int b = 0; b < HBLOCKS; ++b) {
        unsigned int w = partials[(size_t)b * HWORDS + wid];
        prefix[(size_t)b * HWORDS + wid] = run;
        run += w;                        // packed per-byte add, no carry
    }
    int4 o;
    o.x = (int)(run & 0xffu); o.y = (int)((run >> 8) & 0xffu);
    o.z = (int)((run >> 16) & 0xffu); o.w = (int)(run >> 24);
    *(int4*)(deg + (wid << 2)) = o;
}

// fill csr using LDS atomics only: LDS starts at this block's packed prefix,
// atomicAdd returns the exact slot. Zero global atomics.
__global__ void k_fill(const int* __restrict__ src, const int* __restrict__ dst,
                       const unsigned int* __restrict__ prefix,
                       unsigned short* __restrict__ csr) {
    __shared__ unsigned int h[HWORDS];
    int t = threadIdx.x;
    const unsigned int* prow = prefix + (size_t)blockIdx.x * HWORDS;
    for (int w = t; w < HWORDS; w += 256) h[w] = prow[w];
    __syncthreads();
    int base = blockIdx.x * HCHUNK;
    for (int i = t; i < HCHUNK; i += 256) {
        int s = src[base + i], d = dst[base + i];
        int sh = (d & 3) << 3;
        unsigned int old = atomicAdd(&h[d >> 2], 1u << sh);
        int slot = (int)((old >> sh) & 0xffu);
        csr[(d << 6) + slot] = (unsigned short)s;
    }
}

// norms + pad each csr row to a multiple of 8 with the zero-sentinel index
__global__ void k_norms(const int* __restrict__ deg_out, const int* __restrict__ deg_in,
                        float* ns, float* nd, float* c,
                        unsigned short* __restrict__ csr, int n) {
    int i = blockIdx.x * 256 + threadIdx.x;
    if (i < n) {
        int dov = deg_out[i]; if (dov < 1) dov = 1;
        int div_ = deg_in[i]; if (div_ < 1) div_ = 1;
        float a = 1.0f / sqrtf((float)dov);
        float b = 1.0f / sqrtf((float)div_);
        ns[i] = a; nd[i] = b; c[i] = a * b;
        int di = deg_in[i];
        int npad = (di + 7) & ~7;
        for (int p = di; p < npad; ++p) csr[(i << 6) + p] = (unsigned short)ZROW;
    }
}

// ---------------- weight folding + sentinel-row zeroing ----------------
// blocks 0..63: W13 = W1@W3 ; block 64: bb = b1@W3 ; block 65: zero sentinel rows

__global__ void k_weights(const float* __restrict__ W1, const float* __restrict__ b1,
                          const float* __restrict__ W3,
                          float* __restrict__ W13, float* __restrict__ bb,
                          float* __restrict__ Y0, float* __restrict__ Y1) {
    if (blockIdx.x == 65) {
        int t = threadIdx.x;
        if (t < DOUT) {
            Y0[((size_t)ZROW << 6) + t] = 0.f;
            Y1[((size_t)ZROW << 6) + t] = 0.f;
        }
        return;
    }
    if (blockIdx.x == 64) {
        int j = threadIdx.x;
        if (j < DOUT) {
            float s = 0.f;
            for (int k = 0; k < DHID; ++k) s += b1[k] * W3[k * DOUT + j];
            bb[j] = s;
        }
        return;
    }
    int idx = blockIdx.x * 256 + threadIdx.x;  // 16384 outputs
    int i = idx >> 6, j = idx & 63;
    float s = 0.f;
    for (int k = 0; k < DHID; ++k) s += W1[i * DHID + k] * W3[k * DOUT + j];
    W13[idx] = s;
}

// ---------------- dense GEMM: Y[50000,64] = ns ∘ (X[50000,256] @ W13[256,64]) ----------------

__global__ void k_gemm(const float* __restrict__ X, const float* __restrict__ W13,
                       const float* __restrict__ ns, float* __restrict__ Y) {
    __shared__ float As[16][68];   // [k][row], padded
    __shared__ float Bs[16][64];   // [k][col]
    int tid = threadIdx.x;
    int tx = tid & 15, ty = tid >> 4;
    int row0 = blockIdx.x * 64;
    float acc[4][4];
#pragma unroll
    for (int i = 0; i < 4; ++i)
#pragma unroll
        for (int j = 0; j < 4; ++j) acc[i][j] = 0.f;

    int lr = tid >> 2;            // 0..63 row within tile
    int lk = (tid & 3) << 2;      // 0,4,8,12
    int arow = row0 + lr;
    if (arow > N_NODES - 1) arow = N_NODES - 1;   // clamp: garbage rows never stored

    for (int k0 = 0; k0 < DIN; k0 += 16) {
        float4 a = *(const float4*)(X + (size_t)arow * DIN + k0 + lk);
        As[lk + 0][lr] = a.x; As[lk + 1][lr] = a.y;
        As[lk + 2][lr] = a.z; As[lk + 3][lr] = a.w;
        float4 b = *(const float4*)(W13 + (size_t)(k0 + (tid >> 4)) * DOUT + ((tid & 15) << 2));
        *(float4*)&Bs[tid >> 4][(tid & 15) << 2] = b;
        __syncthreads();
#pragma unroll
        for (int k = 0; k < 16; ++k) {
            float4 av = *(const float4*)&As[k][ty << 2];
            float4 bv = *(const float4*)&Bs[k][tx << 2];
            float ar[4] = {av.x, av.y, av.z, av.w};
            float br[4] = {bv.x, bv.y, bv.z, bv.w};
#pragma unroll
            for (int i = 0; i < 4; ++i)
#pragma unroll
                for (int j = 0; j < 4; ++j) acc[i][j] += ar[i] * br[j];
        }
        __syncthreads();
    }
#pragma unroll
    for (int i = 0; i < 4; ++i) {
        int row = row0 + (ty << 2) + i;
        if (row < N_NODES) {
            float nsr = ns[row];
            float4 o;
            o.x = acc[i][0] * nsr; o.y = acc[i][1] * nsr;
            o.z = acc[i][2] * nsr; o.w = acc[i][3] * nsr;
            *(float4*)(Y + (size_t)row * DOUT + (tx << 2)) = o;
        }
    }
}

// ---------------- pull-mode SpMM, D=64: one wave per node, lane = column ----------------
// csr rows padded to a multiple of 8 with ZROW (x[ZROW]=0) -> branchless 8-deep
// unrolled loop: 8 readlane broadcasts -> 8 saddr gathers in flight -> 8 adds.
// MODE 0: y = c*acc + ns*bb[lane] ; MODE 1: y = c*acc ; MODE 2: y = nd*acc + b3[lane]

template <int MODE>
__global__ void k_spmm(const float* __restrict__ x, float* __restrict__ y,
                       const unsigned short* __restrict__ csr,
                       const int* __restrict__ cnt,
                       const float* __restrict__ c, const float* __restrict__ ns,
                       const float* __restrict__ nd,
                       const float* __restrict__ bb, const float* __restrict__ b3) {
    int node = blockIdx.x * 4 + (threadIdx.x >> 6);   // grid = N/4 exactly
    int lane = threadIdx.x & 63;
    int npad = (cnt[node] + 7) & ~7;
    int sv = csr[(node << 6) + lane];     // whole padded edge list, one 128B load
    const float* xl = x + lane;
    float acc = 0.f;
    for (int j = 0; j < npad; j += 8) {
        int a0 = __builtin_amdgcn_readlane(sv, j);
        int a1 = __builtin_amdgcn_readlane(sv, j + 1);
        int a2 = __builtin_amdgcn_readlane(sv, j + 2);
        int a3 = __builtin_amdgcn_readlane(sv, j + 3);
        int a4 = __builtin_amdgcn_readlane(sv, j + 4);
        int a5 = __builtin_amdgcn_readlane(sv, j + 5);
        int a6 = __builtin_amdgcn_readlane(sv, j + 6);
        int a7 = __builtin_amdgcn_readlane(sv, j + 7);
        float t0 = xl[(size_t)a0 << 6];
        float t1 = xl[(size_t)a1 << 6];
        float t2 = xl[(size_t)a2 << 6];
        float t3 = xl[(size_t)a3 << 6];
        float t4 = xl[(size_t)a4 << 6];
        float t5 = xl[(size_t)a5 << 6];
        float t6 = xl[(size_t)a6 << 6];
        float t7 = xl[(size_t)a7 << 6];
        acc += t0; acc += t1; acc += t2; acc += t3;
        acc += t4; acc += t5; acc += t6; acc += t7;
    }
    float r;
    if (MODE == 0)      r = c[node] * acc + ns[node] * bb[lane];
    else if (MODE == 1) r = c[node] * acc;
    else                r = nd[node] * acc + b3[lane];
    y[(node << 6) + lane] = r;
}

// ---------------- launcher ----------------

extern "C" void kernel_launch(void* const* d_in, const int* in_sizes, int n_in,
                              void* d_out, int out_size, void* d_ws, size_t ws_size,
                              hipStream_t stream) {
    const float* X   = (const float*)d_in[0];
    const int*   src = (const int*)d_in[1];
    const int*   dst = (const int*)d_in[2];
    const float* W1  = (const float*)d_in[3];
    const float* b1  = (const float*)d_in[4];
    const float* W3  = (const float*)d_in[5];
    const float* b3  = (const float*)d_in[6];
    float* out = (float*)d_out;

    char* ws = (char*)d_ws;
    size_t off = 0;
    auto alloc = [&](size_t bytes) -> void* {
        void* p = ws + off;
        off = (off + bytes + 255) & ~(size_t)255;
        return p;
    };
    // big buffers, time-multiplexed (stream order guarantees safety):
    //   bufA: partialsS (hist src) -> prefixD -> Y1
    //   bufB: partialsD (hist dst) -> Y0
    const size_t BIGSZ = (size_t)(N_NODES + 1) * DOUT * 4;   // >= HBLOCKS*HWORDS*4
    char* bufA = (char*)alloc(BIGSZ);
    char* bufB = (char*)alloc(BIGSZ);
    int*            deg_out = (int*)alloc((size_t)N_NODES * 4);
    int*            deg_in  = (int*)alloc((size_t)N_NODES * 4);
    unsigned short* csr     = (unsigned short*)alloc((size_t)N_NODES * CSTRIDE * 2);
    float*          ns      = (float*)alloc((size_t)N_NODES * 4);
    float*          nd      = (float*)alloc((size_t)N_NODES * 4);
    float*          cc      = (float*)alloc((size_t)N_NODES * 4);
    float*          W13     = (float*)alloc((size_t)DIN * DOUT * 4);
    float*          bb      = (float*)alloc(DOUT * 4);

    unsigned int* pS   = (unsigned int*)bufA;   // src partial histograms
    unsigned int* pD   = (unsigned int*)bufB;   // dst partial histograms
    unsigned int* pref = (unsigned int*)bufA;   // per-(block,node) packed offsets
    float*        Y0   = (float*)bufB;
    float*        Y1   = (float*)bufA;

    const int nblk = (N_NODES + 255) / 256;   // 196
    const int hblk = (HWORDS + 255) / 256;    // 49

    k_hist<<<HBLOCKS, 256, 0, stream>>>(src, pS);
    k_hreduce<<<hblk, 256, 0, stream>>>(pS, deg_out);          // pS dead after this
    k_hist<<<HBLOCKS, 256, 0, stream>>>(dst, pD);
    k_hprefix<<<hblk, 256, 0, stream>>>(pD, pref, deg_in);     // pD dead after this
    k_fill<<<HBLOCKS, 256, 0, stream>>>(src, dst, pref, csr);  // pref dead after this
    k_norms<<<nblk, 256, 0, stream>>>(deg_out, deg_in, ns, nd, cc, csr, N_NODES);

    k_weights<<<66, 256, 0, stream>>>(W1, b1, W3, W13, bb, Y0, Y1);

    // Y0 = ns ∘ (X @ (W1@W3))
    k_gemm<<<(N_NODES + 63) / 64, 256, 0, stream>>>(X, W13, ns, Y0);

    // 6 propagation passes; bias bb injected in pass 1, b3 in pass 6
    k_spmm<0><<<N_NODES / 4, 256, 0, stream>>>(Y0, Y1, csr, deg_in, cc, ns, nd, bb, b3);
    k_spmm<1><<<N_NODES / 4, 256, 0, stream>>>(Y1, Y0, csr, deg_in, cc, ns, nd, bb, b3);
    k_spmm<1><<<N_NODES / 4, 256, 0, stream>>>(Y0, Y1, csr, deg_in, cc, ns, nd, bb, b3);
    k_spmm<1><<<N_NODES / 4, 256, 0, stream>>>(Y1, Y0, csr, deg_in, cc, ns, nd, bb, b3);
    k_spmm<1><<<N_NODES / 4, 256, 0, stream>>>(Y0, Y1, csr, deg_in, cc, ns, nd, bb, b3);
    k_spmm<2><<<N_NODES / 4, 256, 0, stream>>>(Y1, out, csr, deg_in, cc, ns, nd, bb, b3);
}